// Round 1
// baseline (772.636 us; speedup 1.0000x reference)
//
#include <hip/hip_runtime.h>
#include <hip/hip_bf16.h>

// Problem constants (match reference)
#define NN 50000
#define EE 800000
#define DD 128
#define HH 128
#define GG 64

// ---------------- ws layout (bytes) ----------------
// [deg:N int][cursor:N int][gcnt:G int][pooled:G*128 f32]  <- zeroed region
// [csr_off:N+1 int (padded)][csr_src:E int][dinv:N f32][h:N*128 f32][g:N*128 f32]
#define OFF_DEG      0
#define OFF_CURSOR   (OFF_DEG + NN*4)
#define OFF_GCNT     (OFF_CURSOR + NN*4)
#define OFF_POOLED   (OFF_GCNT + GG*4)
#define ZERO_BYTES   (OFF_POOLED + GG*HH*4)
#define OFF_CSROFF   (ZERO_BYTES)
#define OFF_CSRSRC   (OFF_CSROFF + ((NN+1)*4 + 12)/16*16)
#define OFF_DINV     (OFF_CSRSRC + EE*4)
#define OFF_H        (OFF_DINV + NN*4)
#define OFF_G        (OFF_H + NN*HH*4)

// ---------------- kernels ----------------

__global__ __launch_bounds__(256) void count_kernel(
    const int* __restrict__ ei, const int* __restrict__ batch,
    int* __restrict__ deg, int* __restrict__ gcnt)
{
    int i = blockIdx.x * blockDim.x + threadIdx.x;
    if (i < EE) atomicAdd(&deg[ei[EE + i]], 1);   // dst in-degree (real edges)
    if (i < NN) atomicAdd(&gcnt[batch[i]], 1);
}

// single-block exclusive prefix sum of deg -> csr_off, plus dinv = rsqrt(deg+1)
__global__ __launch_bounds__(1024) void prefix_kernel(
    const int* __restrict__ deg, int* __restrict__ off, float* __restrict__ dinv)
{
    __shared__ int smem[1024];
    __shared__ int carry_s;
    int tid = threadIdx.x;
    if (tid == 0) carry_s = 0;
    __syncthreads();
    for (int base = 0; base < NN; base += 1024) {
        int i = base + tid;
        int v = (i < NN) ? deg[i] : 0;
        if (i < NN) dinv[i] = rsqrtf((float)(v + 1));  // +1 self loop
        smem[tid] = v;
        __syncthreads();
        #pragma unroll
        for (int ofs = 1; ofs < 1024; ofs <<= 1) {
            int t = (tid >= ofs) ? smem[tid - ofs] : 0;
            __syncthreads();
            smem[tid] += t;
            __syncthreads();
        }
        int c = carry_s;
        if (i < NN) off[i] = c + smem[tid] - v;  // exclusive
        __syncthreads();
        if (tid == 0) carry_s = c + smem[1023];
        __syncthreads();
    }
    if (tid == 0) off[NN] = carry_s;
}

__global__ __launch_bounds__(256) void fill_csr_kernel(
    const int* __restrict__ ei, const int* __restrict__ off,
    int* __restrict__ cursor, int* __restrict__ csr_src)
{
    int e = blockIdx.x * blockDim.x + threadIdx.x;
    if (e < EE) {
        int s = ei[e];
        int d = ei[EE + e];
        int p = atomicAdd(&cursor[d], 1);
        csr_src[off[d] + p] = s;
    }
}

// C[n][128] = A[n][0:128] @ W[128][128], f32, BM=64, full K staged in 4 chunks
__global__ __launch_bounds__(256) void gemm_f32_kernel(
    const float* __restrict__ A, const float* __restrict__ W,
    float* __restrict__ C)
{
    __shared__ float As[64][36];    // padded stride 36 floats (144 B, 16B-aligned)
    __shared__ float Ws[32][132];   // padded stride 132 floats (528 B, 16B-aligned)
    int tid = threadIdx.x;
    int row0 = blockIdx.x * 64;
    int trow = tid >> 5;   // 0..7
    int tcol = tid & 31;   // 0..31
    float acc[8][4];
    #pragma unroll
    for (int r = 0; r < 8; ++r)
        for (int c = 0; c < 4; ++c) acc[r][c] = 0.f;

    for (int kc = 0; kc < 128; kc += 32) {
        {
            int r  = tid >> 3;          // 0..31
            int k4 = (tid & 7) * 4;     // 0..28
            #pragma unroll
            for (int rr = 0; rr < 64; rr += 32) {
                int row = row0 + r + rr;
                float4 v = make_float4(0.f, 0.f, 0.f, 0.f);
                if (row < NN) v = *(const float4*)(A + (size_t)row * 128 + kc + k4);
                *(float4*)(&As[r + rr][k4]) = v;
            }
            int wr = tid >> 5;          // 0..7
            int wc = (tid & 31) * 4;
            #pragma unroll
            for (int rr = 0; rr < 32; rr += 8) {
                float4 v = *(const float4*)(W + (size_t)(kc + wr + rr) * 128 + wc);
                *(float4*)(&Ws[wr + rr][wc]) = v;
            }
        }
        __syncthreads();
        #pragma unroll
        for (int kk = 0; kk < 32; ++kk) {
            float4 b = *(const float4*)(&Ws[kk][tcol * 4]);
            float a[8];
            #pragma unroll
            for (int r = 0; r < 8; ++r) a[r] = As[trow * 8 + r][kk];
            #pragma unroll
            for (int r = 0; r < 8; ++r) {
                acc[r][0] += a[r] * b.x;
                acc[r][1] += a[r] * b.y;
                acc[r][2] += a[r] * b.z;
                acc[r][3] += a[r] * b.w;
            }
        }
        __syncthreads();
    }
    #pragma unroll
    for (int r = 0; r < 8; ++r) {
        int row = row0 + trow * 8 + r;
        if (row < NN) {
            float4 v = make_float4(acc[r][0], acc[r][1], acc[r][2], acc[r][3]);
            *(float4*)(C + (size_t)row * 128 + tcol * 4) = v;
        }
    }
}

// aggregation: out[n] = (sum_{s in N(n)} h[s]*dinv[s] + h[n]*dinv[n]) * dinv[n] + b
// one wave per node, lane handles 2 columns (float2)
__global__ __launch_bounds__(256) void agg1_kernel(
    const float* __restrict__ h, const int* __restrict__ csr_off,
    const int* __restrict__ csr_src, const float* __restrict__ dinv,
    const float* __restrict__ bias, float* __restrict__ out)
{
    int node = blockIdx.x * 4 + (threadIdx.x >> 6);
    if (node >= NN) return;
    int lane = threadIdx.x & 63;
    float dn = dinv[node];
    const float2* hp = (const float2*)(h + (size_t)node * 128);
    float2 hv = hp[lane];
    float ax = hv.x * dn, ay = hv.y * dn;   // self loop (x dn again at end)
    int e0 = csr_off[node], e1 = csr_off[node + 1];
    for (int e = e0; e < e1; ++e) {
        int s = csr_src[e];
        float ds = dinv[s];
        const float2* sp = (const float2*)(h + (size_t)s * 128);
        float2 v = sp[lane];
        ax += v.x * ds;
        ay += v.y * ds;
    }
    float ox = ax * dn + bias[lane * 2];
    float oy = ay * dn + bias[lane * 2 + 1];
    ox = fmaxf(ox, 0.f);
    oy = fmaxf(oy, 0.f);
    float2* op = (float2*)(out + (size_t)node * 128);
    op[lane] = make_float2(ox, oy);
}

// conv2 aggregation fused with graph pooling (atomic accumulate per graph)
__global__ __launch_bounds__(256) void agg2_pool_kernel(
    const float* __restrict__ h, const int* __restrict__ csr_off,
    const int* __restrict__ csr_src, const float* __restrict__ dinv,
    const float* __restrict__ bias, const int* __restrict__ batch,
    float* __restrict__ pooled)
{
    int node = blockIdx.x * 4 + (threadIdx.x >> 6);
    if (node >= NN) return;
    int lane = threadIdx.x & 63;
    float dn = dinv[node];
    const float2* hp = (const float2*)(h + (size_t)node * 128);
    float2 hv = hp[lane];
    float ax = hv.x * dn, ay = hv.y * dn;
    int e0 = csr_off[node], e1 = csr_off[node + 1];
    for (int e = e0; e < e1; ++e) {
        int s = csr_src[e];
        float ds = dinv[s];
        const float2* sp = (const float2*)(h + (size_t)s * 128);
        float2 v = sp[lane];
        ax += v.x * ds;
        ay += v.y * ds;
    }
    float ox = ax * dn + bias[lane * 2];
    float oy = ay * dn + bias[lane * 2 + 1];
    int g = batch[node];
    atomicAdd(&pooled[(size_t)g * 128 + lane * 2], ox);
    atomicAdd(&pooled[(size_t)g * 128 + lane * 2 + 1], oy);
}

__global__ __launch_bounds__(256) void finalize_kernel(
    const float* __restrict__ pooled, const int* __restrict__ gcnt,
    float* __restrict__ out)
{
    int i = blockIdx.x * blockDim.x + threadIdx.x;
    if (i < GG * HH) {
        int g = i >> 7;
        float c = (float)max(gcnt[g], 1);
        out[i] = pooled[i] / c;
    }
}

// ---------------- launcher ----------------

extern "C" void kernel_launch(void* const* d_in, const int* in_sizes, int n_in,
                              void* d_out, int out_size, void* d_ws, size_t ws_size,
                              hipStream_t stream)
{
    const float* x     = (const float*)d_in[0];
    const int*   ei    = (const int*)d_in[1];
    const int*   batch = (const int*)d_in[2];
    const float* W1    = (const float*)d_in[3];
    const float* b1    = (const float*)d_in[4];
    const float* W2    = (const float*)d_in[5];
    const float* b2    = (const float*)d_in[6];
    float* out = (float*)d_out;

    char* ws = (char*)d_ws;
    int*   deg     = (int*)(ws + OFF_DEG);
    int*   cursor  = (int*)(ws + OFF_CURSOR);
    int*   gcnt    = (int*)(ws + OFF_GCNT);
    float* pooled  = (float*)(ws + OFF_POOLED);
    int*   csr_off = (int*)(ws + OFF_CSROFF);
    int*   csr_src = (int*)(ws + OFF_CSRSRC);
    float* dinv    = (float*)(ws + OFF_DINV);
    float* hbuf    = (float*)(ws + OFF_H);
    float* gbuf    = (float*)(ws + OFF_G);

    // zero deg/cursor/gcnt/pooled in one memset
    hipMemsetAsync(ws, 0, ZERO_BYTES, stream);

    // degree + graph counts
    count_kernel<<<(EE + 255) / 256, 256, 0, stream>>>(ei, batch, deg, gcnt);

    // prefix sum -> csr_off, dinv
    prefix_kernel<<<1, 1024, 0, stream>>>(deg, csr_off, dinv);

    // scatter edges into CSR (by dst)
    fill_csr_kernel<<<(EE + 255) / 256, 256, 0, stream>>>(ei, csr_off, cursor, csr_src);

    // conv1: h = x @ W1
    gemm_f32_kernel<<<(NN + 63) / 64, 256, 0, stream>>>(x, W1, hbuf);
    // g = relu(agg(h) + b1)
    agg1_kernel<<<(NN + 3) / 4, 256, 0, stream>>>(hbuf, csr_off, csr_src, dinv, b1, gbuf);

    // conv2: h = g @ W2
    gemm_f32_kernel<<<(NN + 63) / 64, 256, 0, stream>>>(gbuf, W2, hbuf);
    // pooled += agg(h) + b2 (per graph)
    agg2_pool_kernel<<<(NN + 3) / 4, 256, 0, stream>>>(hbuf, csr_off, csr_src, dinv, b2, batch, pooled);

    // out = pooled / cnt
    finalize_kernel<<<(GG * HH + 255) / 256, 256, 0, stream>>>(pooled, gcnt, out);
}

// Round 2
// 634.318 us; speedup vs baseline: 1.2181x; 1.2181x over previous
//
#include <hip/hip_runtime.h>
#include <hip/hip_bf16.h>

// Problem constants (match reference)
#define NN 50000
#define EE 800000
#define DD 128
#define HH 128
#define GG 64

// ---------------- ws layout (bytes) ----------------
// zeroed at start: [deg:N int][cursor:N int][gcnt:G int][pooled:G*128 f32]
// then: [csr_off:N+1][csr_src:E][dinv:N f32][h:N*128 f32][g:N*128 f32]
// r[N*64 f32] aliases g (dead after gemm2), zeroed separately.
#define OFF_DEG      0
#define OFF_CURSOR   (OFF_DEG + NN*4)
#define OFF_GCNT     (OFF_CURSOR + NN*4)
#define OFF_POOLED   (OFF_GCNT + GG*4)
#define ZERO_BYTES   (OFF_POOLED + GG*HH*4)
#define OFF_CSROFF   (ZERO_BYTES)
#define OFF_CSRSRC   (OFF_CSROFF + ((NN+1)*4 + 12)/16*16)
#define OFF_DINV     (OFF_CSRSRC + EE*4)
#define OFF_H        (OFF_DINV + NN*4)
#define OFF_G        (OFF_H + NN*HH*4)

// ---------------- kernels ----------------

__global__ __launch_bounds__(256) void count_kernel(
    const int* __restrict__ ei, const int* __restrict__ batch,
    int* __restrict__ deg, int* __restrict__ gcnt)
{
    int i = blockIdx.x * blockDim.x + threadIdx.x;
    if (i < EE) atomicAdd(&deg[ei[EE + i]], 1);   // dst in-degree (real edges)
    if (i < NN) atomicAdd(&gcnt[batch[i]], 1);
}

// single-block exclusive prefix sum of deg -> csr_off, plus dinv = rsqrt(deg+1)
// shfl-based wave scans: 3 barriers per 1024-chunk instead of ~20
__global__ __launch_bounds__(1024) void prefix_kernel(
    const int* __restrict__ deg, int* __restrict__ off, float* __restrict__ dinv)
{
    __shared__ int wsum[16];
    __shared__ int carry_s;
    int tid  = threadIdx.x;
    int wid  = tid >> 6;
    int lane = tid & 63;
    if (tid == 0) carry_s = 0;
    __syncthreads();
    for (int base = 0; base < NN; base += 1024) {
        int i = base + tid;
        int v = (i < NN) ? deg[i] : 0;
        if (i < NN) dinv[i] = rsqrtf((float)(v + 1));  // +1 self loop
        // inclusive wave scan of v
        int x = v;
        #pragma unroll
        for (int ofs = 1; ofs < 64; ofs <<= 1) {
            int t = __shfl_up(x, ofs, 64);
            if (lane >= ofs) x += t;
        }
        if (lane == 63) wsum[wid] = x;
        __syncthreads();
        if (wid == 0) {
            int s = (lane < 16) ? wsum[lane] : 0;
            #pragma unroll
            for (int ofs = 1; ofs < 16; ofs <<= 1) {
                int t = __shfl_up(s, ofs, 64);
                if (lane >= ofs) s += t;
            }
            if (lane < 16) wsum[lane] = s;
        }
        __syncthreads();
        int woff = (wid > 0) ? wsum[wid - 1] : 0;
        int c = carry_s;
        if (i < NN) off[i] = c + woff + x - v;  // exclusive
        __syncthreads();               // all reads of wsum/carry_s done
        if (tid == 0) carry_s = c + wsum[15];
        // next-iter reads of carry_s are after the next barrier inside the loop
        __syncthreads();
    }
    if (tid == 0) off[NN] = carry_s;
}

__global__ __launch_bounds__(256) void fill_csr_kernel(
    const int* __restrict__ ei, const int* __restrict__ off,
    int* __restrict__ cursor, int* __restrict__ csr_src)
{
    int e = blockIdx.x * blockDim.x + threadIdx.x;
    if (e < EE) {
        int s = ei[e];
        int d = ei[EE + e];
        int p = atomicAdd(&cursor[d], 1);
        csr_src[off[d] + p] = s;
    }
}

// C[n][128] = A[n][0:128] @ W[128][128], f32, BM=64
__global__ __launch_bounds__(256) void gemm_f32_kernel(
    const float* __restrict__ A, const float* __restrict__ W,
    float* __restrict__ C)
{
    __shared__ float As[64][36];
    __shared__ float Ws[32][132];
    int tid = threadIdx.x;
    int row0 = blockIdx.x * 64;
    int trow = tid >> 5;   // 0..7
    int tcol = tid & 31;   // 0..31
    float acc[8][4];
    #pragma unroll
    for (int r = 0; r < 8; ++r)
        for (int c = 0; c < 4; ++c) acc[r][c] = 0.f;

    for (int kc = 0; kc < 128; kc += 32) {
        {
            int r  = tid >> 3;          // 0..31
            int k4 = (tid & 7) * 4;     // 0..28
            #pragma unroll
            for (int rr = 0; rr < 64; rr += 32) {
                int row = row0 + r + rr;
                float4 v = make_float4(0.f, 0.f, 0.f, 0.f);
                if (row < NN) v = *(const float4*)(A + (size_t)row * 128 + kc + k4);
                *(float4*)(&As[r + rr][k4]) = v;
            }
            int wr = tid >> 5;          // 0..7
            int wc = (tid & 31) * 4;
            #pragma unroll
            for (int rr = 0; rr < 32; rr += 8) {
                float4 v = *(const float4*)(W + (size_t)(kc + wr + rr) * 128 + wc);
                *(float4*)(&Ws[wr + rr][wc]) = v;
            }
        }
        __syncthreads();
        #pragma unroll
        for (int kk = 0; kk < 32; ++kk) {
            float4 b = *(const float4*)(&Ws[kk][tcol * 4]);
            float a[8];
            #pragma unroll
            for (int r = 0; r < 8; ++r) a[r] = As[trow * 8 + r][kk];
            #pragma unroll
            for (int r = 0; r < 8; ++r) {
                acc[r][0] += a[r] * b.x;
                acc[r][1] += a[r] * b.y;
                acc[r][2] += a[r] * b.z;
                acc[r][3] += a[r] * b.w;
            }
        }
        __syncthreads();
    }
    #pragma unroll
    for (int r = 0; r < 8; ++r) {
        int row = row0 + trow * 8 + r;
        if (row < NN) {
            float4 v = make_float4(acc[r][0], acc[r][1], acc[r][2], acc[r][3]);
            *(float4*)(C + (size_t)row * 128 + tcol * 4) = v;
        }
    }
}

// conv1 aggregation: out[n] = relu((sum_{s in N(n)} h[s]*dinv[s] + h[n]*dinv[n]) * dinv[n] + b)
// one wave per node, lane = 2 columns (float2); edge loop unrolled x4 for MLP
__global__ __launch_bounds__(256) void agg1_kernel(
    const float* __restrict__ h, const int* __restrict__ csr_off,
    const int* __restrict__ csr_src, const float* __restrict__ dinv,
    const float* __restrict__ bias, float* __restrict__ out)
{
    int node = blockIdx.x * 4 + (threadIdx.x >> 6);
    if (node >= NN) return;
    int lane = threadIdx.x & 63;
    float dn = dinv[node];
    const float2* hp = (const float2*)h;
    float2 hv = hp[(size_t)node * 64 + lane];
    float ax = hv.x * dn, ay = hv.y * dn;   // self loop
    int e0 = csr_off[node], e1 = csr_off[node + 1];
    int e = e0;
    for (; e + 4 <= e1; e += 4) {
        int s0 = csr_src[e],     s1 = csr_src[e + 1];
        int s2 = csr_src[e + 2], s3 = csr_src[e + 3];
        float w0 = dinv[s0], w1 = dinv[s1], w2 = dinv[s2], w3 = dinv[s3];
        float2 v0 = hp[(size_t)s0 * 64 + lane];
        float2 v1 = hp[(size_t)s1 * 64 + lane];
        float2 v2 = hp[(size_t)s2 * 64 + lane];
        float2 v3 = hp[(size_t)s3 * 64 + lane];
        ax += v0.x * w0 + v1.x * w1 + v2.x * w2 + v3.x * w3;
        ay += v0.y * w0 + v1.y * w1 + v2.y * w2 + v3.y * w3;
    }
    for (; e < e1; ++e) {
        int s = csr_src[e];
        float w = dinv[s];
        float2 v = hp[(size_t)s * 64 + lane];
        ax += v.x * w;
        ay += v.y * w;
    }
    float ox = fmaxf(ax * dn + bias[lane * 2],     0.f);
    float oy = fmaxf(ay * dn + bias[lane * 2 + 1], 0.f);
    ((float2*)out)[(size_t)node * 64 + lane] = make_float2(ox, oy);
}

// r[s][g] = sum_{edges s->d, batch[d]=g} dinv[s]*dinv[d]  +  [batch[s]=g]*dinv[s]^2
__global__ __launch_bounds__(256) void r_build_kernel(
    const int* __restrict__ ei, const int* __restrict__ batch,
    const float* __restrict__ dinv, float* __restrict__ r)
{
    int i = blockIdx.x * blockDim.x + threadIdx.x;
    if (i < EE) {
        int s = ei[i];
        int d = ei[EE + i];
        atomicAdd(&r[(size_t)s * GG + batch[d]], dinv[s] * dinv[d]);
    }
    if (i < NN) {
        atomicAdd(&r[(size_t)i * GG + batch[i]], dinv[i] * dinv[i]);
    }
}

// pooled[g][f] += sum_k r[k][g] * h2[k][f]   (M=64, N=128, K=50000 split over blocks)
#define KC 200
__global__ __launch_bounds__(256) void pool_gemm_kernel(
    const float* __restrict__ h, const float* __restrict__ r,
    float* __restrict__ pooled)
{
    int k0 = blockIdx.x * KC;
    int k1 = min(k0 + KC, NN);
    int tid = threadIdx.x;
    int gg = tid >> 5;      // graphs gg*8 .. gg*8+7
    int ff = tid & 31;      // features ff*4 .. ff*4+3
    float acc[8][4];
    #pragma unroll
    for (int i = 0; i < 8; ++i)
        for (int j = 0; j < 4; ++j) acc[i][j] = 0.f;

    for (int k = k0; k < k1; ++k) {
        float4 hv = *(const float4*)(h + (size_t)k * HH + ff * 4);
        const float* rk = r + (size_t)k * GG + gg * 8;
        #pragma unroll
        for (int i = 0; i < 8; ++i) {
            float rv = rk[i];
            acc[i][0] += rv * hv.x;
            acc[i][1] += rv * hv.y;
            acc[i][2] += rv * hv.z;
            acc[i][3] += rv * hv.w;
        }
    }
    #pragma unroll
    for (int i = 0; i < 8; ++i)
        #pragma unroll
        for (int j = 0; j < 4; ++j)
            atomicAdd(&pooled[(size_t)(gg * 8 + i) * HH + ff * 4 + j], acc[i][j]);
}

// out = (pooled + cnt*b2) / max(cnt,1)
__global__ __launch_bounds__(256) void finalize_kernel(
    const float* __restrict__ pooled, const int* __restrict__ gcnt,
    const float* __restrict__ b2, float* __restrict__ out)
{
    int i = blockIdx.x * blockDim.x + threadIdx.x;
    if (i < GG * HH) {
        int g = i >> 7;
        int f = i & 127;
        float c = (float)gcnt[g];
        out[i] = (pooled[i] + c * b2[f]) / fmaxf(c, 1.0f);
    }
}

// ---------------- launcher ----------------

extern "C" void kernel_launch(void* const* d_in, const int* in_sizes, int n_in,
                              void* d_out, int out_size, void* d_ws, size_t ws_size,
                              hipStream_t stream)
{
    const float* x     = (const float*)d_in[0];
    const int*   ei    = (const int*)d_in[1];
    const int*   batch = (const int*)d_in[2];
    const float* W1    = (const float*)d_in[3];
    const float* b1    = (const float*)d_in[4];
    const float* W2    = (const float*)d_in[5];
    const float* b2    = (const float*)d_in[6];
    float* out = (float*)d_out;

    char* ws = (char*)d_ws;
    int*   deg     = (int*)(ws + OFF_DEG);
    int*   gcnt    = (int*)(ws + OFF_GCNT);
    float* pooled  = (float*)(ws + OFF_POOLED);
    int*   csr_off = (int*)(ws + OFF_CSROFF);
    int*   csr_src = (int*)(ws + OFF_CSRSRC);
    float* dinv    = (float*)(ws + OFF_DINV);
    float* hbuf    = (float*)(ws + OFF_H);
    float* gbuf    = (float*)(ws + OFF_G);
    float* rbuf    = gbuf;   // aliases gbuf (dead after gemm2); N*64 f32 = 12.8 MB

    // zero deg/cursor/gcnt/pooled
    hipMemsetAsync(ws, 0, ZERO_BYTES, stream);

    // degree + graph counts
    count_kernel<<<(EE + 255) / 256, 256, 0, stream>>>(ei, batch, deg, gcnt);

    // prefix sum -> csr_off, dinv
    prefix_kernel<<<1, 1024, 0, stream>>>(deg, csr_off, dinv);

    // scatter edges into CSR (by dst)
    fill_csr_kernel<<<(EE + 255) / 256, 256, 0, stream>>>(
        ei, csr_off, (int*)(ws + OFF_CURSOR), csr_src);

    // conv1: h = x @ W1
    gemm_f32_kernel<<<(NN + 63) / 64, 256, 0, stream>>>(x, W1, hbuf);
    // g = relu(agg(h) + b1)
    agg1_kernel<<<(NN + 3) / 4, 256, 0, stream>>>(hbuf, csr_off, csr_src, dinv, b1, gbuf);

    // conv2 GEMM: h2 = g @ W2
    gemm_f32_kernel<<<(NN + 63) / 64, 256, 0, stream>>>(gbuf, W2, hbuf);

    // r weights (alias gbuf, now dead): zero then scatter
    hipMemsetAsync(rbuf, 0, (size_t)NN * GG * 4, stream);
    r_build_kernel<<<(EE + 255) / 256, 256, 0, stream>>>(ei, batch, dinv, rbuf);

    // pooled[g][f] = sum_k r[k][g] * h2[k][f]
    pool_gemm_kernel<<<(NN + KC - 1) / KC, 256, 0, stream>>>(hbuf, rbuf, pooled);

    // out = (pooled + cnt*b2) / max(cnt,1)
    finalize_kernel<<<(GG * HH + 255) / 256, 256, 0, stream>>>(pooled, gcnt, b2, out);
}

// Round 3
// 375.671 us; speedup vs baseline: 2.0567x; 1.6885x over previous
//
#include <hip/hip_runtime.h>
#include <hip/hip_bf16.h>

// Problem constants (match reference)
#define NN 50000
#define EE 800000
#define HH 128
#define GG 64

#define NB 196          // dst buckets = (50000>>8)+1
#define CHUNK 4096      // edges per partition block
#define NBLK ((EE + CHUNK - 1) / CHUNK)
#define CAP 8192        // LDS key capacity in k4 (bucket avg 4096, max ~4500)

// ---------------- ws layout (bytes) ----------------
#define OFF_BHIST   0                          // NB ints (zeroed via memset)
#define OFF_CURSOR  (OFF_BHIST + NB*4)         // NB ints (init in k2)
#define OFF_BOFF    (OFF_CURSOR + NB*4)        // NB+1 ints
#define OFF_GSTART  (OFF_BOFF + (NB+1)*4)      // GG+1 ints
#define OFF_CSROFF  (((OFF_GSTART + (GG+1)*4) + 15)/16*16)   // NN+1 ints
#define OFF_DINV    (((OFF_CSROFF + (NN+1)*4) + 15)/16*16)   // NN f32
#define OFF_KEYA    (((OFF_DINV + NN*4) + 15)/16*16)         // EE u32
#define OFF_KEYB    (OFF_KEYA + EE*4)                        // EE u32
#define OFF_H       (((OFF_KEYB + EE*4) + 15)/16*16)         // NN*128 f32
#define OFF_G       (OFF_H + NN*HH*4)                        // NN*128 f32

// ---------------- kernels ----------------

// k1: global bucket histogram of dst>>8 (per-block LDS hist, hot-atomic merge)
__global__ __launch_bounds__(256) void k1_hist(
    const int* __restrict__ ei, int* __restrict__ bhist)
{
    __shared__ int h[NB];
    int tid = threadIdx.x;
    for (int j = tid; j < NB; j += 256) h[j] = 0;
    __syncthreads();
    int base = blockIdx.x * CHUNK;
    int end = min(base + CHUNK, EE);
    for (int i = base + tid; i < end; i += 256)
        atomicAdd(&h[ei[EE + i] >> 8], 1);
    __syncthreads();
    for (int j = tid; j < NB; j += 256)
        if (h[j]) atomicAdd(&bhist[j], h[j]);
}

// k2: exclusive scan of 196 bucket counts -> boff, cursor
__global__ __launch_bounds__(256) void k2_scan(
    const int* __restrict__ bhist, int* __restrict__ boff, int* __restrict__ cursor)
{
    __shared__ int v[NB + 1];
    int tid = threadIdx.x;
    if (tid < NB) v[tid] = bhist[tid];
    __syncthreads();
    if (tid == 0) {
        int run = 0;
        for (int j = 0; j < NB; ++j) { int t = v[j]; v[j] = run; run += t; }
        v[NB] = run;
    }
    __syncthreads();
    if (tid < NB) { boff[tid] = v[tid]; cursor[tid] = v[tid]; }
    if (tid == NB) boff[NB] = v[NB];
}

// k3: partition edges into dst>>8 buckets. Block reserves a contiguous range per
// bucket with ONE hot atomic, then plain writes of packed (dst<<16|src).
__global__ __launch_bounds__(256) void k3_scatter(
    const int* __restrict__ ei, int* __restrict__ cursor, unsigned* __restrict__ keyA)
{
    __shared__ int h[NB];
    __shared__ int basev[NB];
    __shared__ int c[NB];
    int tid = threadIdx.x;
    for (int j = tid; j < NB; j += 256) { h[j] = 0; c[j] = 0; }
    __syncthreads();
    int base = blockIdx.x * CHUNK;
    int end = min(base + CHUNK, EE);
    for (int i = base + tid; i < end; i += 256)
        atomicAdd(&h[ei[EE + i] >> 8], 1);
    __syncthreads();
    for (int j = tid; j < NB; j += 256)
        if (h[j]) basev[j] = atomicAdd(&cursor[j], h[j]);
    __syncthreads();
    for (int i = base + tid; i < end; i += 256) {
        int s = ei[i];
        int d = ei[EE + i];
        int b = d >> 8;
        int r = atomicAdd(&c[b], 1);               // LDS atomic
        keyA[basev[b] + r] = ((unsigned)d << 16) | (unsigned)s;
    }
}

// k4: per-bucket LDS counting sort by dst&255 -> keyB fully dst-grouped.
// Also emits csr_off, dinv directly from the histogram.
__global__ __launch_bounds__(256) void k4_sort(
    const unsigned* __restrict__ keyA, const int* __restrict__ boff,
    unsigned* __restrict__ keyB, int* __restrict__ csr_off, float* __restrict__ dinv)
{
    __shared__ unsigned keys[CAP];
    __shared__ int h[256];
    __shared__ int off[256];
    int b = blockIdx.x, tid = threadIdx.x;
    int e0 = boff[b], e1 = boff[b + 1], n = e1 - e0;
    h[tid] = 0;
    __syncthreads();
    for (int i = tid; i < n; i += 256) {
        unsigned k = keyA[e0 + i];
        if (i < CAP) keys[i] = k;
        atomicAdd(&h[(k >> 16) & 255], 1);
    }
    __syncthreads();
    if (tid == 0) {
        int run = 0;
        for (int j = 0; j < 256; ++j) { int t = h[j]; off[j] = run; run += t; }
    }
    __syncthreads();
    int d = (b << 8) + tid;
    if (d < NN) {
        csr_off[d] = e0 + off[tid];
        dinv[d] = rsqrtf((float)(h[tid] + 1));     // +1 self loop
    }
    if (b == 0 && tid == 0) csr_off[NN] = EE;
    __syncthreads();
    h[tid] = 0;
    __syncthreads();
    for (int i = tid; i < n; i += 256) {
        unsigned k = (i < CAP) ? keys[i] : keyA[e0 + i];
        int lo = (k >> 16) & 255;
        int r = atomicAdd(&h[lo], 1);              // LDS atomic
        keyB[e0 + off[lo] + r] = k;
    }
}

// gstart[g] = lower_bound(batch, g); batch is sorted. gstart[GG] = NN.
__global__ __launch_bounds__(128) void gstart_kernel(
    const int* __restrict__ batch, int* __restrict__ gstart)
{
    int g = threadIdx.x;
    if (g > GG) return;
    int lo = 0, hi = NN;
    while (lo < hi) {
        int mid = (lo + hi) >> 1;
        if (batch[mid] < g) lo = mid + 1; else hi = mid;
    }
    gstart[g] = lo;
}

// C[n][128] = (A[n] @ W) * dinv[n], f32, BM=64
__global__ __launch_bounds__(256) void gemm_scaled_kernel(
    const float* __restrict__ A, const float* __restrict__ W,
    const float* __restrict__ dinv, float* __restrict__ C)
{
    __shared__ float As[64][36];
    __shared__ float Ws[32][132];
    int tid = threadIdx.x;
    int row0 = blockIdx.x * 64;
    int trow = tid >> 5;   // 0..7
    int tcol = tid & 31;   // 0..31
    float acc[8][4];
    #pragma unroll
    for (int r = 0; r < 8; ++r)
        for (int c = 0; c < 4; ++c) acc[r][c] = 0.f;

    for (int kc = 0; kc < 128; kc += 32) {
        {
            int r  = tid >> 3;
            int k4 = (tid & 7) * 4;
            #pragma unroll
            for (int rr = 0; rr < 64; rr += 32) {
                int row = row0 + r + rr;
                float4 v = make_float4(0.f, 0.f, 0.f, 0.f);
                if (row < NN) v = *(const float4*)(A + (size_t)row * 128 + kc + k4);
                *(float4*)(&As[r + rr][k4]) = v;
            }
            int wr = tid >> 5;
            int wc = (tid & 31) * 4;
            #pragma unroll
            for (int rr = 0; rr < 32; rr += 8) {
                float4 v = *(const float4*)(W + (size_t)(kc + wr + rr) * 128 + wc);
                *(float4*)(&Ws[wr + rr][wc]) = v;
            }
        }
        __syncthreads();
        #pragma unroll
        for (int kk = 0; kk < 32; ++kk) {
            float4 bb = *(const float4*)(&Ws[kk][tcol * 4]);
            float a[8];
            #pragma unroll
            for (int r = 0; r < 8; ++r) a[r] = As[trow * 8 + r][kk];
            #pragma unroll
            for (int r = 0; r < 8; ++r) {
                acc[r][0] += a[r] * bb.x;
                acc[r][1] += a[r] * bb.y;
                acc[r][2] += a[r] * bb.z;
                acc[r][3] += a[r] * bb.w;
            }
        }
        __syncthreads();
    }
    #pragma unroll
    for (int r = 0; r < 8; ++r) {
        int row = row0 + trow * 8 + r;
        if (row < NN) {
            float dn = dinv[row];
            float4 v = make_float4(acc[r][0] * dn, acc[r][1] * dn,
                                   acc[r][2] * dn, acc[r][3] * dn);
            *(float4*)(C + (size_t)row * 128 + tcol * 4) = v;
        }
    }
}

// aggregation over dinv-prescaled rows h':
//   sum = h'[n] + sum_{s in N(n)} h'[s];  out = FIN ? relu(dn*sum + bias) : dn*sum
template<bool FIN>
__global__ __launch_bounds__(256) void agg_kernel(
    const float* __restrict__ h, const unsigned* __restrict__ keyB,
    const int* __restrict__ csr_off, const float* __restrict__ dinv,
    const float* __restrict__ bias, float* __restrict__ out)
{
    int node = blockIdx.x * 4 + (threadIdx.x >> 6);
    if (node >= NN) return;
    int lane = threadIdx.x & 63;
    float dn = dinv[node];
    const float2* hp = (const float2*)h;
    float2 hv = hp[(size_t)node * 64 + lane];
    float ax = hv.x, ay = hv.y;               // self term (already dinv-scaled)
    int e = csr_off[node], e1 = csr_off[node + 1];
    for (; e + 4 <= e1; e += 4) {
        int s0 = keyB[e]     & 0xFFFF;
        int s1 = keyB[e + 1] & 0xFFFF;
        int s2 = keyB[e + 2] & 0xFFFF;
        int s3 = keyB[e + 3] & 0xFFFF;
        float2 v0 = hp[(size_t)s0 * 64 + lane];
        float2 v1 = hp[(size_t)s1 * 64 + lane];
        float2 v2 = hp[(size_t)s2 * 64 + lane];
        float2 v3 = hp[(size_t)s3 * 64 + lane];
        ax += v0.x + v1.x + v2.x + v3.x;
        ay += v0.y + v1.y + v2.y + v3.y;
    }
    for (; e < e1; ++e) {
        int s = keyB[e] & 0xFFFF;
        float2 v = hp[(size_t)s * 64 + lane];
        ax += v.x;
        ay += v.y;
    }
    float ox = ax * dn, oy = ay * dn;
    if (FIN) {
        ox = fmaxf(ox + bias[lane * 2],     0.f);
        oy = fmaxf(oy + bias[lane * 2 + 1], 0.f);
    }
    ((float2*)out)[(size_t)node * 64 + lane] = make_float2(ox, oy);
}

// segmented mean-pool over sorted batch: out[g][f] = (sum h3 + cnt*b2)/max(cnt,1)
__global__ __launch_bounds__(128) void pool_kernel(
    const float* __restrict__ h3, const int* __restrict__ gstart,
    const float* __restrict__ b2, float* __restrict__ out)
{
    int g = blockIdx.x, f = threadIdx.x;
    int s = gstart[g], e = gstart[g + 1];
    float a0 = 0.f, a1 = 0.f, a2 = 0.f, a3 = 0.f;
    int n = s;
    for (; n + 4 <= e; n += 4) {
        a0 += h3[(size_t)(n    ) * HH + f];
        a1 += h3[(size_t)(n + 1) * HH + f];
        a2 += h3[(size_t)(n + 2) * HH + f];
        a3 += h3[(size_t)(n + 3) * HH + f];
    }
    for (; n < e; ++n) a0 += h3[(size_t)n * HH + f];
    float acc = (a0 + a1) + (a2 + a3);
    float cnt = (float)(e - s);
    out[g * HH + f] = (acc + cnt * b2[f]) / fmaxf(cnt, 1.f);
}

// ---------------- launcher ----------------

extern "C" void kernel_launch(void* const* d_in, const int* in_sizes, int n_in,
                              void* d_out, int out_size, void* d_ws, size_t ws_size,
                              hipStream_t stream)
{
    const float* x     = (const float*)d_in[0];
    const int*   ei    = (const int*)d_in[1];
    const int*   batch = (const int*)d_in[2];
    const float* W1    = (const float*)d_in[3];
    const float* b1    = (const float*)d_in[4];
    const float* W2    = (const float*)d_in[5];
    const float* b2    = (const float*)d_in[6];
    float* out = (float*)d_out;

    char* ws = (char*)d_ws;
    int*      bhist   = (int*)(ws + OFF_BHIST);
    int*      cursor  = (int*)(ws + OFF_CURSOR);
    int*      boff    = (int*)(ws + OFF_BOFF);
    int*      gstart  = (int*)(ws + OFF_GSTART);
    int*      csr_off = (int*)(ws + OFF_CSROFF);
    float*    dinv    = (float*)(ws + OFF_DINV);
    unsigned* keyA    = (unsigned*)(ws + OFF_KEYA);
    unsigned* keyB    = (unsigned*)(ws + OFF_KEYB);
    float*    hbuf    = (float*)(ws + OFF_H);
    float*    gbuf    = (float*)(ws + OFF_G);

    // zero the 196 bucket counters only
    hipMemsetAsync(bhist, 0, NB * 4, stream);

    // bucket sort by dst (196 buckets, then in-LDS counting sort) -> CSR + dinv
    k1_hist<<<NBLK, 256, 0, stream>>>(ei, bhist);
    k2_scan<<<1, 256, 0, stream>>>(bhist, boff, cursor);
    k3_scatter<<<NBLK, 256, 0, stream>>>(ei, cursor, keyA);
    k4_sort<<<NB, 256, 0, stream>>>(keyA, boff, keyB, csr_off, dinv);

    // graph segment starts from sorted batch
    gstart_kernel<<<1, 128, 0, stream>>>(batch, gstart);

    // conv1: h' = (x @ W1) * dinv ; g = relu(dn * (self+neighbors) + b1)
    gemm_scaled_kernel<<<(NN + 63) / 64, 256, 0, stream>>>(x, W1, dinv, hbuf);
    agg_kernel<true><<<(NN + 3) / 4, 256, 0, stream>>>(hbuf, keyB, csr_off, dinv, b1, gbuf);

    // conv2: h2' = (g @ W2) * dinv ; h3 = dn * (self+neighbors)
    gemm_scaled_kernel<<<(NN + 63) / 64, 256, 0, stream>>>(gbuf, W2, dinv, hbuf);
    agg_kernel<false><<<(NN + 3) / 4, 256, 0, stream>>>(hbuf, keyB, csr_off, dinv, b2, gbuf);

    // segmented mean pool (+b2) over sorted batch
    pool_kernel<<<GG, 128, 0, stream>>>(gbuf, gstart, b2, out);
}

// Round 4
// 306.308 us; speedup vs baseline: 2.5224x; 1.2264x over previous
//
#include <hip/hip_runtime.h>
#include <hip/hip_bf16.h>

// Problem constants (match reference)
#define NN 50000
#define EE 800000
#define HH 128
#define GG 64

#define NB 196          // dst buckets = (50000>>8)+1
#define CHUNK 4096      // edges per partition block
#define NBLK ((EE + CHUNK - 1) / CHUNK)
#define CAP 8192        // LDS key capacity in k4

typedef __attribute__((ext_vector_type(8))) short short8;
typedef __attribute__((ext_vector_type(4))) float f32x4;

__device__ __forceinline__ unsigned short f2bf(float f) {
    unsigned u = __float_as_uint(f);
    return (unsigned short)((u + 0x7FFFu + ((u >> 16) & 1u)) >> 16);  // RNE
}
__device__ __forceinline__ float bflo(unsigned p) { return __uint_as_float(p << 16); }
__device__ __forceinline__ float bfhi(unsigned p) { return __uint_as_float(p & 0xFFFF0000u); }
__device__ __forceinline__ float bfu(unsigned short u) { return __uint_as_float(((unsigned)u) << 16); }

// ---------------- ws layout (bytes) ----------------
#define OFF_BHIST   0                                        // NB ints (memset 0)
#define OFF_CURSOR  (OFF_BHIST + NB*4)                       // NB ints (init in k2)
#define OFF_BOFF    (OFF_CURSOR + NB*4)                      // NB+1 ints
#define OFF_GSTART  (OFF_BOFF + (NB+1)*4)                    // GG+1 ints
#define OFF_CSROFF  (((OFF_GSTART + (GG+1)*4) + 15)/16*16)   // NN+1 ints
#define OFF_DINV    (((OFF_CSROFF + (NN+1)*4) + 15)/16*16)   // NN f32
#define OFF_WT1     (((OFF_DINV + NN*4) + 15)/16*16)         // 128*128 bf16
#define OFF_WT2     (OFF_WT1 + HH*HH*2)                      // 128*128 bf16
#define OFF_KEYA    (OFF_WT2 + HH*HH*2)                      // EE u32
#define OFF_KEYB    (OFF_KEYA + EE*4)                        // EE u32
#define OFF_H       (OFF_KEYB + EE*4)                        // NN*128 bf16
#define OFF_G       (OFF_H + NN*HH*2)                        // NN*128 bf16

// ---------------- sort pipeline ----------------

// k1: global bucket histogram of dst>>8 (per-block LDS hist, hot-atomic merge)
__global__ __launch_bounds__(256) void k1_hist(
    const int* __restrict__ ei, int* __restrict__ bhist)
{
    __shared__ int h[NB];
    int tid = threadIdx.x;
    for (int j = tid; j < NB; j += 256) h[j] = 0;
    __syncthreads();
    int base = blockIdx.x * CHUNK;
    int end = min(base + CHUNK, EE);
    for (int i = base + tid; i < end; i += 256)
        atomicAdd(&h[ei[EE + i] >> 8], 1);
    __syncthreads();
    for (int j = tid; j < NB; j += 256)
        if (h[j]) atomicAdd(&bhist[j], h[j]);
}

// k2: exclusive scan of 196 bucket counts -> boff, cursor
__global__ __launch_bounds__(256) void k2_scan(
    const int* __restrict__ bhist, int* __restrict__ boff, int* __restrict__ cursor)
{
    __shared__ int v[NB + 1];
    int tid = threadIdx.x;
    if (tid < NB) v[tid] = bhist[tid];
    __syncthreads();
    if (tid == 0) {
        int run = 0;
        for (int j = 0; j < NB; ++j) { int t = v[j]; v[j] = run; run += t; }
        v[NB] = run;
    }
    __syncthreads();
    if (tid < NB) { boff[tid] = v[tid]; cursor[tid] = v[tid]; }
    if (tid == NB) boff[NB] = v[NB];
}

// k3: partition edges into dst>>8 buckets (one hot atomic per block-bucket)
__global__ __launch_bounds__(256) void k3_scatter(
    const int* __restrict__ ei, int* __restrict__ cursor, unsigned* __restrict__ keyA)
{
    __shared__ int h[NB];
    __shared__ int basev[NB];
    __shared__ int c[NB];
    int tid = threadIdx.x;
    for (int j = tid; j < NB; j += 256) { h[j] = 0; c[j] = 0; }
    __syncthreads();
    int base = blockIdx.x * CHUNK;
    int end = min(base + CHUNK, EE);
    for (int i = base + tid; i < end; i += 256)
        atomicAdd(&h[ei[EE + i] >> 8], 1);
    __syncthreads();
    for (int j = tid; j < NB; j += 256)
        if (h[j]) basev[j] = atomicAdd(&cursor[j], h[j]);
    __syncthreads();
    for (int i = base + tid; i < end; i += 256) {
        int s = ei[i];
        int d = ei[EE + i];
        int b = d >> 8;
        int r = atomicAdd(&c[b], 1);               // LDS atomic
        keyA[basev[b] + r] = ((unsigned)d << 16) | (unsigned)s;
    }
}

// k4: per-bucket LDS counting sort by dst&255 -> keyB dst-grouped; emits csr_off/dinv
__global__ __launch_bounds__(256) void k4_sort(
    const unsigned* __restrict__ keyA, const int* __restrict__ boff,
    unsigned* __restrict__ keyB, int* __restrict__ csr_off, float* __restrict__ dinv)
{
    __shared__ unsigned keys[CAP];
    __shared__ int h[256];
    __shared__ int off[256];
    int b = blockIdx.x, tid = threadIdx.x;
    int e0 = boff[b], e1 = boff[b + 1], n = e1 - e0;
    h[tid] = 0;
    __syncthreads();
    for (int i = tid; i < n; i += 256) {
        unsigned k = keyA[e0 + i];
        if (i < CAP) keys[i] = k;
        atomicAdd(&h[(k >> 16) & 255], 1);
    }
    __syncthreads();
    if (tid == 0) {
        int run = 0;
        for (int j = 0; j < 256; ++j) { int t = h[j]; off[j] = run; run += t; }
    }
    __syncthreads();
    int d = (b << 8) + tid;
    if (d < NN) {
        csr_off[d] = e0 + off[tid];
        dinv[d] = rsqrtf((float)(h[tid] + 1));     // +1 self loop
    }
    if (b == 0 && tid == 0) csr_off[NN] = EE;
    __syncthreads();
    h[tid] = 0;
    __syncthreads();
    for (int i = tid; i < n; i += 256) {
        unsigned k = (i < CAP) ? keys[i] : keyA[e0 + i];
        int lo = (k >> 16) & 255;
        int r = atomicAdd(&h[lo], 1);              // LDS atomic
        keyB[e0 + off[lo] + r] = k;
    }
}

// gstart[g] = lower_bound(batch, g); batch is sorted.
__global__ __launch_bounds__(128) void gstart_kernel(
    const int* __restrict__ batch, int* __restrict__ gstart)
{
    int g = threadIdx.x;
    if (g > GG) return;
    int lo = 0, hi = NN;
    while (lo < hi) {
        int mid = (lo + hi) >> 1;
        if (batch[mid] < g) lo = mid + 1; else hi = mid;
    }
    gstart[g] = lo;
}

// W [k][n] f32 -> Wt [n][k] bf16 (both layers, tiny)
__global__ __launch_bounds__(256) void wcast_kernel(
    const float* __restrict__ W1, const float* __restrict__ W2,
    unsigned short* __restrict__ Wt1, unsigned short* __restrict__ Wt2)
{
    int i = blockIdx.x * 256 + threadIdx.x;
    if (i < HH * HH) {
        int r = i >> 7, c = i & 127;
        Wt1[c * HH + r] = f2bf(W1[i]);
        Wt2[c * HH + r] = f2bf(W2[i]);
    }
}

// ---------------- MFMA GEMM: C[row] = bf16((A[row] @ W) * dinv[row]) ----------------
// Block: 64 rows x 128 cols, 4 waves; wave w owns cols [w*32, w*32+32).
// B-frags (W^T rows) held in registers for the whole block. No LDS.
// Verified m92 pattern: a/b frags = 8 contiguous bf16 per lane from row-major
// A / B^T; C/D mapping col=lane&15, row=(lane>>4)*4+reg.
template<bool F32SRC>
__global__ __launch_bounds__(256) void gemm_mfma_kernel(
    const void* __restrict__ Asrc, const unsigned short* __restrict__ Wt,
    const float* __restrict__ dinv, unsigned short* __restrict__ C)
{
    int tid = threadIdx.x;
    int w  = tid >> 6;       // wave -> col block
    int l  = tid & 63;
    int lr = l & 15;
    int lg = l >> 4;         // 0..3

    short8 bfrag[2][4];
    #pragma unroll
    for (int nt = 0; nt < 2; ++nt)
        #pragma unroll
        for (int kt = 0; kt < 4; ++kt) {
            int n = w * 32 + nt * 16 + lr;
            int k = kt * 32 + lg * 8;
            bfrag[nt][kt] = *(const short8*)(Wt + (size_t)n * HH + k);
        }

    int base0 = blockIdx.x * 64;
    #pragma unroll
    for (int mt = 0; mt < 4; ++mt) {
        int rowA = base0 + mt * 16 + lr;
        short8 afrag[4];
        #pragma unroll
        for (int kt = 0; kt < 4; ++kt) {
            short8 v = {0, 0, 0, 0, 0, 0, 0, 0};
            if (rowA < NN) {
                if (F32SRC) {
                    const float* p = (const float*)Asrc + (size_t)rowA * HH + kt * 32 + lg * 8;
                    f32x4 u0 = *(const f32x4*)p;
                    f32x4 u1 = *(const f32x4*)(p + 4);
                    #pragma unroll
                    for (int j = 0; j < 4; ++j) {
                        v[j]     = (short)f2bf(u0[j]);
                        v[j + 4] = (short)f2bf(u1[j]);
                    }
                } else {
                    v = *(const short8*)((const unsigned short*)Asrc +
                                         (size_t)rowA * HH + kt * 32 + lg * 8);
                }
            }
            afrag[kt] = v;
        }
        f32x4 acc0 = {0.f, 0.f, 0.f, 0.f};
        f32x4 acc1 = {0.f, 0.f, 0.f, 0.f};
        #pragma unroll
        for (int kt = 0; kt < 4; ++kt) {
            acc0 = __builtin_amdgcn_mfma_f32_16x16x32_bf16(afrag[kt], bfrag[0][kt], acc0, 0, 0, 0);
            acc1 = __builtin_amdgcn_mfma_f32_16x16x32_bf16(afrag[kt], bfrag[1][kt], acc1, 0, 0, 0);
        }
        #pragma unroll
        for (int r = 0; r < 4; ++r) {
            int row = base0 + mt * 16 + lg * 4 + r;
            if (row < NN) {
                float dn = dinv[row];
                C[(size_t)row * HH + w * 32 + lr]      = f2bf(acc0[r] * dn);
                C[(size_t)row * HH + w * 32 + 16 + lr] = f2bf(acc1[r] * dn);
            }
        }
    }
}

// ---------------- aggregation (bf16 rows, f32 accumulate) ----------------
// sum = h'[n] + sum_{s in N(n)} h'[s];  out = FIN ? relu(dn*sum + bias) : dn*sum
template<bool FIN>
__global__ __launch_bounds__(256) void agg_kernel(
    const unsigned* __restrict__ hp, const unsigned* __restrict__ keyB,
    const int* __restrict__ csr_off, const float* __restrict__ dinv,
    const float* __restrict__ bias, unsigned* __restrict__ out)
{
    int node = blockIdx.x * 4 + (threadIdx.x >> 6);
    if (node >= NN) return;
    int lane = threadIdx.x & 63;
    float dn = dinv[node];
    unsigned hv = hp[(size_t)node * 64 + lane];
    float ax = bflo(hv), ay = bfhi(hv);       // self term (already dinv-scaled)
    int e = csr_off[node], e1 = csr_off[node + 1];
    for (; e + 4 <= e1; e += 4) {
        int s0 = keyB[e]     & 0xFFFF;
        int s1 = keyB[e + 1] & 0xFFFF;
        int s2 = keyB[e + 2] & 0xFFFF;
        int s3 = keyB[e + 3] & 0xFFFF;
        unsigned v0 = hp[(size_t)s0 * 64 + lane];
        unsigned v1 = hp[(size_t)s1 * 64 + lane];
        unsigned v2 = hp[(size_t)s2 * 64 + lane];
        unsigned v3 = hp[(size_t)s3 * 64 + lane];
        ax += bflo(v0) + bflo(v1) + bflo(v2) + bflo(v3);
        ay += bfhi(v0) + bfhi(v1) + bfhi(v2) + bfhi(v3);
    }
    for (; e < e1; ++e) {
        int s = keyB[e] & 0xFFFF;
        unsigned v = hp[(size_t)s * 64 + lane];
        ax += bflo(v);
        ay += bfhi(v);
    }
    float ox = ax * dn, oy = ay * dn;
    if (FIN) {
        ox = fmaxf(ox + bias[lane * 2],     0.f);
        oy = fmaxf(oy + bias[lane * 2 + 1], 0.f);
    }
    out[(size_t)node * 64 + lane] = (unsigned)f2bf(ox) | ((unsigned)f2bf(oy) << 16);
}

// segmented mean-pool: out[g][f] = (sum h3 + cnt*b2[f]) / max(cnt,1)
__global__ __launch_bounds__(128) void pool_kernel(
    const unsigned short* __restrict__ h3, const int* __restrict__ gstart,
    const float* __restrict__ b2, float* __restrict__ out)
{
    int g = blockIdx.x, f = threadIdx.x;
    int s = gstart[g], e = gstart[g + 1];
    float a0 = 0.f, a1 = 0.f, a2 = 0.f, a3 = 0.f;
    int n = s;
    for (; n + 4 <= e; n += 4) {
        a0 += bfu(h3[(size_t)(n    ) * HH + f]);
        a1 += bfu(h3[(size_t)(n + 1) * HH + f]);
        a2 += bfu(h3[(size_t)(n + 2) * HH + f]);
        a3 += bfu(h3[(size_t)(n + 3) * HH + f]);
    }
    for (; n < e; ++n) a0 += bfu(h3[(size_t)n * HH + f]);
    float acc = (a0 + a1) + (a2 + a3);
    float cnt = (float)(e - s);
    out[g * HH + f] = (acc + cnt * b2[f]) / fmaxf(cnt, 1.f);
}

// ---------------- launcher ----------------

extern "C" void kernel_launch(void* const* d_in, const int* in_sizes, int n_in,
                              void* d_out, int out_size, void* d_ws, size_t ws_size,
                              hipStream_t stream)
{
    const float* x     = (const float*)d_in[0];
    const int*   ei    = (const int*)d_in[1];
    const int*   batch = (const int*)d_in[2];
    const float* W1    = (const float*)d_in[3];
    const float* b1    = (const float*)d_in[4];
    const float* W2    = (const float*)d_in[5];
    const float* b2    = (const float*)d_in[6];
    float* out = (float*)d_out;

    char* ws = (char*)d_ws;
    int*            bhist   = (int*)(ws + OFF_BHIST);
    int*            cursor  = (int*)(ws + OFF_CURSOR);
    int*            boff    = (int*)(ws + OFF_BOFF);
    int*            gstart  = (int*)(ws + OFF_GSTART);
    int*            csr_off = (int*)(ws + OFF_CSROFF);
    float*          dinv    = (float*)(ws + OFF_DINV);
    unsigned short* Wt1     = (unsigned short*)(ws + OFF_WT1);
    unsigned short* Wt2     = (unsigned short*)(ws + OFF_WT2);
    unsigned*       keyA    = (unsigned*)(ws + OFF_KEYA);
    unsigned*       keyB    = (unsigned*)(ws + OFF_KEYB);
    unsigned short* hbuf    = (unsigned short*)(ws + OFF_H);
    unsigned short* gbuf    = (unsigned short*)(ws + OFF_G);

    hipMemsetAsync(bhist, 0, NB * 4, stream);

    // bucket sort by dst -> CSR + dinv
    k1_hist<<<NBLK, 256, 0, stream>>>(ei, bhist);
    k2_scan<<<1, 256, 0, stream>>>(bhist, boff, cursor);
    k3_scatter<<<NBLK, 256, 0, stream>>>(ei, cursor, keyA);
    k4_sort<<<NB, 256, 0, stream>>>(keyA, boff, keyB, csr_off, dinv);

    gstart_kernel<<<1, 128, 0, stream>>>(batch, gstart);
    wcast_kernel<<<(HH * HH + 255) / 256, 256, 0, stream>>>(W1, W2, Wt1, Wt2);

    // conv1: h' = bf16((x @ W1) * dinv); g = bf16(relu(dn*(self+nbrs) + b1))
    gemm_mfma_kernel<true><<<(NN + 63) / 64, 256, 0, stream>>>(x, Wt1, dinv, hbuf);
    agg_kernel<true><<<(NN + 3) / 4, 256, 0, stream>>>(
        (const unsigned*)hbuf, keyB, csr_off, dinv, b1, (unsigned*)gbuf);

    // conv2: h2' = bf16((g @ W2) * dinv); h3 = bf16(dn*(self+nbrs))
    gemm_mfma_kernel<false><<<(NN + 63) / 64, 256, 0, stream>>>(gbuf, Wt2, dinv, hbuf);
    agg_kernel<false><<<(NN + 3) / 4, 256, 0, stream>>>(
        (const unsigned*)hbuf, keyB, csr_off, dinv, b2, (unsigned*)gbuf);

    // mean pool (+b2) over sorted batch
    pool_kernel<<<GG, 128, 0, stream>>>(gbuf, gstart, b2, out);
}

// Round 5
// 293.714 us; speedup vs baseline: 2.6306x; 1.0429x over previous
//
#include <hip/hip_runtime.h>
#include <hip/hip_bf16.h>

// Problem constants (match reference)
#define NN 50000
#define EE 800000
#define HH 128
#define GG 64

#define NB 196          // dst buckets = (50000>>8)+1
#define CHUNK 4096      // edges per partition block
#define NBLK ((EE + CHUNK - 1) / CHUNK)
#define CAP 8192        // LDS key capacity in k4
#define PCH 128         // rows per pool-partial block

typedef __attribute__((ext_vector_type(8))) short short8;
typedef __attribute__((ext_vector_type(4))) float f32x4;

__device__ __forceinline__ unsigned short f2bf(float f) {
    unsigned u = __float_as_uint(f);
    return (unsigned short)((u + 0x7FFFu + ((u >> 16) & 1u)) >> 16);  // RNE
}
__device__ __forceinline__ float bflo(unsigned p) { return __uint_as_float(p << 16); }
__device__ __forceinline__ float bfhi(unsigned p) { return __uint_as_float(p & 0xFFFF0000u); }
__device__ __forceinline__ float bfu(unsigned short u) { return __uint_as_float(((unsigned)u) << 16); }

// ---------------- ws layout (bytes) ----------------
// zeroed region: [bhist NB][pooled G*HH f32]
#define OFF_BHIST   0                                        // NB ints
#define OFF_POOLED  (OFF_BHIST + NB*4)                       // GG*HH f32
#define ZERO_BYTES  (OFF_POOLED + GG*HH*4)
#define OFF_CURSOR  (ZERO_BYTES)                             // NB ints (init in k2)
#define OFF_BOFF    (OFF_CURSOR + NB*4)                      // NB+1 ints
#define OFF_GSTART  (OFF_BOFF + (NB+1)*4)                    // GG+1 ints
#define OFF_CSROFF  (((OFF_GSTART + (GG+1)*4) + 15)/16*16)   // NN+1 ints
#define OFF_DINV    (((OFF_CSROFF + (NN+1)*4) + 15)/16*16)   // NN f32
#define OFF_WT1     (((OFF_DINV + NN*4) + 15)/16*16)         // 128*128 bf16
#define OFF_WT2     (OFF_WT1 + HH*HH*2)                      // 128*128 bf16
#define OFF_KEYA    (OFF_WT2 + HH*HH*2)                      // EE u32
#define OFF_KEYB    (OFF_KEYA + EE*4)                        // EE u32
#define OFF_H       (OFF_KEYB + EE*4)                        // NN*128 bf16
#define OFF_G       (OFF_H + NN*HH*2)                        // NN*128 bf16

// ---------------- sort pipeline ----------------

// k1: global bucket histogram of dst>>8 (per-block LDS hist, hot-atomic merge)
__global__ __launch_bounds__(256) void k1_hist(
    const int* __restrict__ ei, int* __restrict__ bhist)
{
    __shared__ int h[NB];
    int tid = threadIdx.x;
    for (int j = tid; j < NB; j += 256) h[j] = 0;
    __syncthreads();
    int base = blockIdx.x * CHUNK;
    int end = min(base + CHUNK, EE);
    for (int i = base + tid; i < end; i += 256)
        atomicAdd(&h[ei[EE + i] >> 8], 1);
    __syncthreads();
    for (int j = tid; j < NB; j += 256)
        if (h[j]) atomicAdd(&bhist[j], h[j]);
}

// k2: exclusive scan of 196 bucket counts -> boff, cursor
__global__ __launch_bounds__(256) void k2_scan(
    const int* __restrict__ bhist, int* __restrict__ boff, int* __restrict__ cursor)
{
    __shared__ int v[NB + 1];
    int tid = threadIdx.x;
    if (tid < NB) v[tid] = bhist[tid];
    __syncthreads();
    if (tid == 0) {
        int run = 0;
        for (int j = 0; j < NB; ++j) { int t = v[j]; v[j] = run; run += t; }
        v[NB] = run;
    }
    __syncthreads();
    if (tid < NB) { boff[tid] = v[tid]; cursor[tid] = v[tid]; }
    if (tid == NB) boff[NB] = v[NB];
}

// k3: partition edges into dst>>8 buckets (one hot atomic per block-bucket)
__global__ __launch_bounds__(256) void k3_scatter(
    const int* __restrict__ ei, int* __restrict__ cursor, unsigned* __restrict__ keyA)
{
    __shared__ int h[NB];
    __shared__ int basev[NB];
    __shared__ int c[NB];
    int tid = threadIdx.x;
    for (int j = tid; j < NB; j += 256) { h[j] = 0; c[j] = 0; }
    __syncthreads();
    int base = blockIdx.x * CHUNK;
    int end = min(base + CHUNK, EE);
    for (int i = base + tid; i < end; i += 256)
        atomicAdd(&h[ei[EE + i] >> 8], 1);
    __syncthreads();
    for (int j = tid; j < NB; j += 256)
        if (h[j]) basev[j] = atomicAdd(&cursor[j], h[j]);
    __syncthreads();
    for (int i = base + tid; i < end; i += 256) {
        int s = ei[i];
        int d = ei[EE + i];
        int b = d >> 8;
        int r = atomicAdd(&c[b], 1);               // LDS atomic
        keyA[basev[b] + r] = ((unsigned)d << 16) | (unsigned)s;
    }
}

// k4: per-bucket LDS counting sort by dst&255 -> keyB dst-grouped; emits csr_off/dinv
__global__ __launch_bounds__(256) void k4_sort(
    const unsigned* __restrict__ keyA, const int* __restrict__ boff,
    unsigned* __restrict__ keyB, int* __restrict__ csr_off, float* __restrict__ dinv)
{
    __shared__ unsigned keys[CAP];
    __shared__ int h[256];
    __shared__ int off[256];
    int b = blockIdx.x, tid = threadIdx.x;
    int e0 = boff[b], e1 = boff[b + 1], n = e1 - e0;
    h[tid] = 0;
    __syncthreads();
    for (int i = tid; i < n; i += 256) {
        unsigned k = keyA[e0 + i];
        if (i < CAP) keys[i] = k;
        atomicAdd(&h[(k >> 16) & 255], 1);
    }
    __syncthreads();
    if (tid == 0) {
        int run = 0;
        for (int j = 0; j < 256; ++j) { int t = h[j]; off[j] = run; run += t; }
    }
    __syncthreads();
    int d = (b << 8) + tid;
    if (d < NN) {
        csr_off[d] = e0 + off[tid];
        dinv[d] = rsqrtf((float)(h[tid] + 1));     // +1 self loop
    }
    if (b == 0 && tid == 0) csr_off[NN] = EE;
    __syncthreads();
    h[tid] = 0;
    __syncthreads();
    for (int i = tid; i < n; i += 256) {
        unsigned k = (i < CAP) ? keys[i] : keyA[e0 + i];
        int lo = (k >> 16) & 255;
        int r = atomicAdd(&h[lo], 1);              // LDS atomic
        keyB[e0 + off[lo] + r] = k;
    }
}

// gstart[g] = lower_bound(batch, g); batch is sorted.
__global__ __launch_bounds__(128) void gstart_kernel(
    const int* __restrict__ batch, int* __restrict__ gstart)
{
    int g = threadIdx.x;
    if (g > GG) return;
    int lo = 0, hi = NN;
    while (lo < hi) {
        int mid = (lo + hi) >> 1;
        if (batch[mid] < g) lo = mid + 1; else hi = mid;
    }
    gstart[g] = lo;
}

// W [k][n] f32 -> Wt [n][k] bf16 (both layers, tiny)
__global__ __launch_bounds__(256) void wcast_kernel(
    const float* __restrict__ W1, const float* __restrict__ W2,
    unsigned short* __restrict__ Wt1, unsigned short* __restrict__ Wt2)
{
    int i = blockIdx.x * 256 + threadIdx.x;
    if (i < HH * HH) {
        int r = i >> 7, c = i & 127;
        Wt1[c * HH + r] = f2bf(W1[i]);
        Wt2[c * HH + r] = f2bf(W2[i]);
    }
}

// ---------------- MFMA GEMM: C[row] = bf16((A[row] @ W) * dinv[row]) ----------------
// Block: 64 rows x 128 cols, 4 waves; wave w owns cols [w*32, w*32+32).
// B-frags (W^T rows) held in registers for the whole block. No LDS.
template<bool F32SRC>
__global__ __launch_bounds__(256) void gemm_mfma_kernel(
    const void* __restrict__ Asrc, const unsigned short* __restrict__ Wt,
    const float* __restrict__ dinv, unsigned short* __restrict__ C)
{
    int tid = threadIdx.x;
    int w  = tid >> 6;       // wave -> col block
    int l  = tid & 63;
    int lr = l & 15;
    int lg = l >> 4;         // 0..3

    short8 bfrag[2][4];
    #pragma unroll
    for (int nt = 0; nt < 2; ++nt)
        #pragma unroll
        for (int kt = 0; kt < 4; ++kt) {
            int n = w * 32 + nt * 16 + lr;
            int k = kt * 32 + lg * 8;
            bfrag[nt][kt] = *(const short8*)(Wt + (size_t)n * HH + k);
        }

    int base0 = blockIdx.x * 64;
    #pragma unroll
    for (int mt = 0; mt < 4; ++mt) {
        int rowA = base0 + mt * 16 + lr;
        short8 afrag[4];
        #pragma unroll
        for (int kt = 0; kt < 4; ++kt) {
            short8 v = {0, 0, 0, 0, 0, 0, 0, 0};
            if (rowA < NN) {
                if (F32SRC) {
                    const float* p = (const float*)Asrc + (size_t)rowA * HH + kt * 32 + lg * 8;
                    f32x4 u0 = *(const f32x4*)p;
                    f32x4 u1 = *(const f32x4*)(p + 4);
                    #pragma unroll
                    for (int j = 0; j < 4; ++j) {
                        v[j]     = (short)f2bf(u0[j]);
                        v[j + 4] = (short)f2bf(u1[j]);
                    }
                } else {
                    v = *(const short8*)((const unsigned short*)Asrc +
                                         (size_t)rowA * HH + kt * 32 + lg * 8);
                }
            }
            afrag[kt] = v;
        }
        f32x4 acc0 = {0.f, 0.f, 0.f, 0.f};
        f32x4 acc1 = {0.f, 0.f, 0.f, 0.f};
        #pragma unroll
        for (int kt = 0; kt < 4; ++kt) {
            acc0 = __builtin_amdgcn_mfma_f32_16x16x32_bf16(afrag[kt], bfrag[0][kt], acc0, 0, 0, 0);
            acc1 = __builtin_amdgcn_mfma_f32_16x16x32_bf16(afrag[kt], bfrag[1][kt], acc1, 0, 0, 0);
        }
        #pragma unroll
        for (int r = 0; r < 4; ++r) {
            int row = base0 + mt * 16 + lg * 4 + r;
            if (row < NN) {
                float dn = dinv[row];
                C[(size_t)row * HH + w * 32 + lr]      = f2bf(acc0[r] * dn);
                C[(size_t)row * HH + w * 32 + 16 + lr] = f2bf(acc1[r] * dn);
            }
        }
    }
}

// ---------------- aggregation (bf16 rows, f32 accumulate) ----------------
// sum = h'[n] + sum_{s in N(n)} h'[s];  out = FIN ? relu(dn*sum + bias) : dn*sum
template<bool FIN>
__global__ __launch_bounds__(256) void agg_kernel(
    const unsigned* __restrict__ hp, const unsigned* __restrict__ keyB,
    const int* __restrict__ csr_off, const float* __restrict__ dinv,
    const float* __restrict__ bias, unsigned* __restrict__ out)
{
    int node = blockIdx.x * 4 + (threadIdx.x >> 6);
    if (node >= NN) return;
    int lane = threadIdx.x & 63;
    float dn = dinv[node];
    unsigned hv = hp[(size_t)node * 64 + lane];
    float ax = bflo(hv), ay = bfhi(hv);       // self term (already dinv-scaled)
    int e = csr_off[node], e1 = csr_off[node + 1];
    for (; e + 8 <= e1; e += 8) {
        int s0 = keyB[e]     & 0xFFFF;
        int s1 = keyB[e + 1] & 0xFFFF;
        int s2 = keyB[e + 2] & 0xFFFF;
        int s3 = keyB[e + 3] & 0xFFFF;
        int s4 = keyB[e + 4] & 0xFFFF;
        int s5 = keyB[e + 5] & 0xFFFF;
        int s6 = keyB[e + 6] & 0xFFFF;
        int s7 = keyB[e + 7] & 0xFFFF;
        unsigned v0 = hp[(size_t)s0 * 64 + lane];
        unsigned v1 = hp[(size_t)s1 * 64 + lane];
        unsigned v2 = hp[(size_t)s2 * 64 + lane];
        unsigned v3 = hp[(size_t)s3 * 64 + lane];
        unsigned v4 = hp[(size_t)s4 * 64 + lane];
        unsigned v5 = hp[(size_t)s5 * 64 + lane];
        unsigned v6 = hp[(size_t)s6 * 64 + lane];
        unsigned v7 = hp[(size_t)s7 * 64 + lane];
        ax += (bflo(v0) + bflo(v1)) + (bflo(v2) + bflo(v3))
            + (bflo(v4) + bflo(v5)) + (bflo(v6) + bflo(v7));
        ay += (bfhi(v0) + bfhi(v1)) + (bfhi(v2) + bfhi(v3))
            + (bfhi(v4) + bfhi(v5)) + (bfhi(v6) + bfhi(v7));
    }
    for (; e < e1; ++e) {
        int s = keyB[e] & 0xFFFF;
        unsigned v = hp[(size_t)s * 64 + lane];
        ax += bflo(v);
        ay += bfhi(v);
    }
    float ox = ax * dn, oy = ay * dn;
    if (FIN) {
        ox = fmaxf(ox + bias[lane * 2],     0.f);
        oy = fmaxf(oy + bias[lane * 2 + 1], 0.f);
    }
    out[(size_t)node * 64 + lane] = (unsigned)f2bf(ox) | ((unsigned)f2bf(oy) << 16);
}

// pool partial: each block owns PCH rows; accumulate per-feature while batch id
// constant (batch is sorted), flush to pooled[g][f] via hot atomics on change.
__global__ __launch_bounds__(128) void pool_partial_kernel(
    const unsigned short* __restrict__ h3, const int* __restrict__ batch,
    float* __restrict__ pooled)
{
    int n0 = blockIdx.x * PCH;
    int n1 = min(n0 + PCH, NN);
    int f = threadIdx.x;
    float acc = 0.f;
    int cur = batch[n0];
    for (int n = n0; n < n1; ++n) {
        int g = batch[n];
        if (g != cur) {
            atomicAdd(&pooled[(size_t)cur * HH + f], acc);
            acc = 0.f;
            cur = g;
        }
        acc += bfu(h3[(size_t)n * HH + f]);
    }
    atomicAdd(&pooled[(size_t)cur * HH + f], acc);
}

// out[g][f] = (pooled + cnt*b2[f]) / max(cnt,1)
__global__ __launch_bounds__(256) void finalize_kernel(
    const float* __restrict__ pooled, const int* __restrict__ gstart,
    const float* __restrict__ b2, float* __restrict__ out)
{
    int i = blockIdx.x * 256 + threadIdx.x;
    if (i < GG * HH) {
        int g = i >> 7;
        int f = i & 127;
        float cnt = (float)(gstart[g + 1] - gstart[g]);
        out[i] = (pooled[i] + cnt * b2[f]) / fmaxf(cnt, 1.f);
    }
}

// ---------------- launcher ----------------

extern "C" void kernel_launch(void* const* d_in, const int* in_sizes, int n_in,
                              void* d_out, int out_size, void* d_ws, size_t ws_size,
                              hipStream_t stream)
{
    const float* x     = (const float*)d_in[0];
    const int*   ei    = (const int*)d_in[1];
    const int*   batch = (const int*)d_in[2];
    const float* W1    = (const float*)d_in[3];
    const float* b1    = (const float*)d_in[4];
    const float* W2    = (const float*)d_in[5];
    const float* b2    = (const float*)d_in[6];
    float* out = (float*)d_out;

    char* ws = (char*)d_ws;
    int*            bhist   = (int*)(ws + OFF_BHIST);
    float*          pooled  = (float*)(ws + OFF_POOLED);
    int*            cursor  = (int*)(ws + OFF_CURSOR);
    int*            boff    = (int*)(ws + OFF_BOFF);
    int*            gstart  = (int*)(ws + OFF_GSTART);
    int*            csr_off = (int*)(ws + OFF_CSROFF);
    float*          dinv    = (float*)(ws + OFF_DINV);
    unsigned short* Wt1     = (unsigned short*)(ws + OFF_WT1);
    unsigned short* Wt2     = (unsigned short*)(ws + OFF_WT2);
    unsigned*       keyA    = (unsigned*)(ws + OFF_KEYA);
    unsigned*       keyB    = (unsigned*)(ws + OFF_KEYB);
    unsigned short* hbuf    = (unsigned short*)(ws + OFF_H);
    unsigned short* gbuf    = (unsigned short*)(ws + OFF_G);

    hipMemsetAsync(ws, 0, ZERO_BYTES, stream);   // bhist + pooled

    // bucket sort by dst -> CSR + dinv
    k1_hist<<<NBLK, 256, 0, stream>>>(ei, bhist);
    k2_scan<<<1, 256, 0, stream>>>(bhist, boff, cursor);
    k3_scatter<<<NBLK, 256, 0, stream>>>(ei, cursor, keyA);
    k4_sort<<<NB, 256, 0, stream>>>(keyA, boff, keyB, csr_off, dinv);

    gstart_kernel<<<1, 128, 0, stream>>>(batch, gstart);
    wcast_kernel<<<(HH * HH + 255) / 256, 256, 0, stream>>>(W1, W2, Wt1, Wt2);

    // conv1: h' = bf16((x @ W1) * dinv); g = bf16(relu(dn*(self+nbrs) + b1))
    gemm_mfma_kernel<true><<<(NN + 63) / 64, 256, 0, stream>>>(x, Wt1, dinv, hbuf);
    agg_kernel<true><<<(NN + 3) / 4, 256, 0, stream>>>(
        (const unsigned*)hbuf, keyB, csr_off, dinv, b1, (unsigned*)gbuf);

    // conv2: h2' = bf16((g @ W2) * dinv); h3 = bf16(dn*(self+nbrs))
    gemm_mfma_kernel<false><<<(NN + 63) / 64, 256, 0, stream>>>(gbuf, Wt2, dinv, hbuf);
    agg_kernel<false><<<(NN + 3) / 4, 256, 0, stream>>>(
        (const unsigned*)hbuf, keyB, csr_off, dinv, b2, (unsigned*)gbuf);

    // mean pool: partial sums + finalize
    pool_partial_kernel<<<(NN + PCH - 1) / PCH, 128, 0, stream>>>(gbuf, batch, pooled);
    finalize_kernel<<<(GG * HH + 255) / 256, 256, 0, stream>>>(pooled, gstart, b2, out);
}